// Round 10
// baseline (58.799 us; speedup 1.0000x reference)
//
#include <hip/hip_runtime.h>

typedef int int4v __attribute__((ext_vector_type(4)));

// Problem constants
#define IN_C    64
#define OUT_C   128
#define KTOT    576
#define N_X     12845056    // x elements (int32) = x8 bytes
#define N_W     73728       // 128*3*3*64
#define N_OUT   25690112
#define NTILES  3136        // 64 images x 7x7 tiles
#define IMGB    200704      // bytes per image in x8 (3136 px * 64)

// prep grid split
#define PW_BLKS 72          // 18432 dwords of packed weights
#define PX_BLKS 12544       // 3211264 dwords of packed x

__device__ __forceinline__ int pack4(int4v a) {
    return (a.x & 0xff) | ((a.y & 0xff) << 8) | ((a.z & 0xff) << 16) | (a.w << 24);
}

// ---------------------------------------------------------------------------
// Fused prep: pack weights into MFMA fragment order AND x into int8 NHWC.
//   w8 dest byte t = ((kt*8 + nt)*64 + lane)*16 + byte
//     holds W[k][n], k = kt*64 + (lane>>4)*16 + byte, n = nt*16 + (lane&15)
//   x8 is a straight int32 -> int8 narrowing of NHWC x.
__global__ __launch_bounds__(256) void prep_kernel(const int* __restrict__ x,
                                                   const int* __restrict__ wgt,
                                                   unsigned int* __restrict__ x8,
                                                   unsigned int* __restrict__ w8) {
    const int bid = blockIdx.x;
    if (bid < PW_BLKS) {
        int t = bid * 256 + threadIdx.x;      // t < 18432
        int d = t << 2;
        int byte = d & 15;
        int lane = (d >> 4) & 63;
        int ntk  = d >> 10;
        int nt   = ntk & 7;
        int kt   = ntk >> 3;
        int k = kt * 64 + ((lane >> 4) << 4) + byte;
        int n = nt * 16 + (lane & 15);
        int4v v = *(const int4v*)(wgt + n * KTOT + k);
        w8[t] = pack4(v);
    } else {
        int i = (bid - PW_BLKS) * 256 + threadIdx.x;   // i < 3211264 exactly
        int4v v = ((const int4v*)x)[i];
        x8[i] = pack4(v);
    }
}

// ---------------------------------------------------------------------------
// Barrier-free streaming MFMA conv. Block = 8x8 pixels x 128 channels,
// 4 waves (wave = 32-channel slice). NO LDS, NO __syncthreads.
// B-fragments (pixels) load DIRECTLY from int8 x8: lane = pixel x quarter is
// exactly the 16x16x64 B layout. Halo reuse is served by L1 (6.4KB working
// set; 4 waves read identical lines). 18 weight fragments held in registers.
// A = weights (M=channels) -> D row = channel -> dwordx4 stores.
__global__ __launch_bounds__(256, 3) void conv_stream_kernel(const char* __restrict__ x8,
                                                             const char* __restrict__ w8,
                                                             const int* __restrict__ bias,
                                                             int* __restrict__ out) {
    const int tid  = threadIdx.x;
    const int lane = tid & 63;
    const int wv   = tid >> 6;
    const int l15  = lane & 15;
    const int l4   = lane >> 4;

    // XCD-chunked bijective swizzle: 3136 = 8 XCDs x 392 (8 whole images).
    const int bid = blockIdx.x;
    const int nb  = (bid & 7) * 392 + (bid >> 3);

    const int n   = nb / 49;
    const int rr  = nb - n * 49;
    const int th  = rr / 7;
    const int tw  = rr - th * 7;
    const int h0  = th * 8;                   // core origin
    const int w0  = tw * 8;

    // ---- 18 weight fragments in registers for the whole block (L2-resident).
    const char* wb = w8 + (((wv * 2) * 64 + lane) << 4);
    int4v wf00, wf01, wf10, wf11, wf20, wf21, wf30, wf31, wf40, wf41;
    int4v wf50, wf51, wf60, wf61, wf70, wf71, wf80, wf81;
    wf00 = *(const int4v*)(wb + 0 * 8192); wf01 = *(const int4v*)(wb + 0 * 8192 + 1024);
    wf10 = *(const int4v*)(wb + 1 * 8192); wf11 = *(const int4v*)(wb + 1 * 8192 + 1024);
    wf20 = *(const int4v*)(wb + 2 * 8192); wf21 = *(const int4v*)(wb + 2 * 8192 + 1024);
    wf30 = *(const int4v*)(wb + 3 * 8192); wf31 = *(const int4v*)(wb + 3 * 8192 + 1024);
    wf40 = *(const int4v*)(wb + 4 * 8192); wf41 = *(const int4v*)(wb + 4 * 8192 + 1024);
    wf50 = *(const int4v*)(wb + 5 * 8192); wf51 = *(const int4v*)(wb + 5 * 8192 + 1024);
    wf60 = *(const int4v*)(wb + 6 * 8192); wf61 = *(const int4v*)(wb + 6 * 8192 + 1024);
    wf70 = *(const int4v*)(wb + 7 * 8192); wf71 = *(const int4v*)(wb + 7 * 8192 + 1024);
    wf80 = *(const int4v*)(wb + 8 * 8192); wf81 = *(const int4v*)(wb + 8 * 8192 + 1024);

    const int chb = wv * 32 + (l4 << 2);
    const int4v bv0 = *(const int4v*)(bias + chb);
    const int4v bv1 = *(const int4v*)(bias + chb + 16);

    const int prl = l15 >> 3;                 // row within 2x8 sub-tile
    const int pc  = l15 & 7;                  // col
    const int gw_base = w0 + pc;              // per-lane column (fixed)
    const char* xn = x8 + (size_t)n * IMGB + (l4 << 4);

    // mt loop: 4 row-pair sub-tiles; fully unrolled, all indexing static.
#pragma unroll
    for (int mt = 0; mt < 4; ++mt) {
        const int rbase = h0 + (mt << 1) + prl;   // lane's output row

        // ---- 9 tap loads (per-lane masked; interior blocks fully valid).
        int4v b0 = {0,0,0,0}, b1 = {0,0,0,0}, b2 = {0,0,0,0};
        int4v b3 = {0,0,0,0}, b4 = {0,0,0,0}, b5 = {0,0,0,0};
        int4v b6 = {0,0,0,0}, b7 = {0,0,0,0}, b8 = {0,0,0,0};
#define TAP(dst, dh, dw)                                                        \
        {                                                                       \
            int gh = rbase + (dh) - 1;                                          \
            int gw = gw_base + (dw) - 1;                                        \
            if (((unsigned)gh < 56u) & ((unsigned)gw < 56u))                    \
                dst = *(const int4v*)(xn + ((gh * 56 + gw) << 6));              \
        }
        TAP(b0, 0, 0) TAP(b1, 0, 1) TAP(b2, 0, 2)
        TAP(b3, 1, 0) TAP(b4, 1, 1) TAP(b5, 1, 2)
        TAP(b6, 2, 0) TAP(b7, 2, 1) TAP(b8, 2, 2)
#undef TAP

        // ---- 18 MFMA: acc over all 9 taps, 2 channel groups.
        int4v a0 = {0,0,0,0}, a1 = {0,0,0,0};
        a0 = __builtin_amdgcn_mfma_i32_16x16x64_i8(wf00, b0, a0, 0, 0, 0);
        a1 = __builtin_amdgcn_mfma_i32_16x16x64_i8(wf01, b0, a1, 0, 0, 0);
        a0 = __builtin_amdgcn_mfma_i32_16x16x64_i8(wf10, b1, a0, 0, 0, 0);
        a1 = __builtin_amdgcn_mfma_i32_16x16x64_i8(wf11, b1, a1, 0, 0, 0);
        a0 = __builtin_amdgcn_mfma_i32_16x16x64_i8(wf20, b2, a0, 0, 0, 0);
        a1 = __builtin_amdgcn_mfma_i32_16x16x64_i8(wf21, b2, a1, 0, 0, 0);
        a0 = __builtin_amdgcn_mfma_i32_16x16x64_i8(wf30, b3, a0, 0, 0, 0);
        a1 = __builtin_amdgcn_mfma_i32_16x16x64_i8(wf31, b3, a1, 0, 0, 0);
        a0 = __builtin_amdgcn_mfma_i32_16x16x64_i8(wf40, b4, a0, 0, 0, 0);
        a1 = __builtin_amdgcn_mfma_i32_16x16x64_i8(wf41, b4, a1, 0, 0, 0);
        a0 = __builtin_amdgcn_mfma_i32_16x16x64_i8(wf50, b5, a0, 0, 0, 0);
        a1 = __builtin_amdgcn_mfma_i32_16x16x64_i8(wf51, b5, a1, 0, 0, 0);
        a0 = __builtin_amdgcn_mfma_i32_16x16x64_i8(wf60, b6, a0, 0, 0, 0);
        a1 = __builtin_amdgcn_mfma_i32_16x16x64_i8(wf61, b6, a1, 0, 0, 0);
        a0 = __builtin_amdgcn_mfma_i32_16x16x64_i8(wf70, b7, a0, 0, 0, 0);
        a1 = __builtin_amdgcn_mfma_i32_16x16x64_i8(wf71, b7, a1, 0, 0, 0);
        a0 = __builtin_amdgcn_mfma_i32_16x16x64_i8(wf80, b8, a0, 0, 0, 0);
        a1 = __builtin_amdgcn_mfma_i32_16x16x64_i8(wf81, b8, a1, 0, 0, 0);

        // ---- Store: D row = 4*l4+reg = channel, col = l15 = pixel.
        int* o = out + (((n * 56 + rbase) * 56 + w0 + pc) << 7) + chb;
        *(int4v*)(o)      = a0 + bv0;
        *(int4v*)(o + 16) = a1 + bv1;
    }
}

// ---------------------------------------------------------------------------
// Fallback (only if workspace is too small): direct conv, 1 thread/output.
__global__ __launch_bounds__(256) void conv_naive_kernel(const int* __restrict__ x,
                                                         const int* __restrict__ wgt,
                                                         const int* __restrict__ bias,
                                                         int* __restrict__ out) {
    int idx = blockIdx.x * 256 + threadIdx.x;
    if (idx >= N_OUT) return;
    int ch  = idx & 127;
    int pix = idx >> 7;
    int n  = pix / 3136;
    int r2 = pix - n * 3136;
    int h  = r2 / 56;
    int w  = r2 - h * 56;
    int acc = bias[ch];
    for (int kh = 0; kh < 3; ++kh) {
        int hxr = h + kh - 1;
        if ((unsigned)hxr >= 56u) continue;
        for (int kw = 0; kw < 3; ++kw) {
            int wx = w + kw - 1;
            if ((unsigned)wx >= 56u) continue;
            const int* xp = x + ((n * 56 + hxr) * 56 + wx) * 64;
            const int* wp = wgt + ch * KTOT + (kh * 3 + kw) * 64;
            for (int ic = 0; ic < 64; ++ic) acc += xp[ic] * wp[ic];
        }
    }
    out[idx] = acc;
}

// ---------------------------------------------------------------------------
extern "C" void kernel_launch(void* const* d_in, const int* in_sizes, int n_in,
                              void* d_out, int out_size, void* d_ws, size_t ws_size,
                              hipStream_t stream) {
    const int* x    = (const int*)d_in[0];
    const int* wgt  = (const int*)d_in[1];
    const int* bias = (const int*)d_in[2];
    int* out = (int*)d_out;

    const size_t need = (size_t)N_X + (size_t)N_W;   // 12,918,784 B
    if (ws_size >= need) {
        char* x8 = (char*)d_ws;              // N_X bytes, int8 NHWC
        char* w8 = (char*)d_ws + N_X;        // N_W bytes, fragment order
        prep_kernel<<<PW_BLKS + PX_BLKS, 256, 0, stream>>>(x, wgt,
                                                           (unsigned int*)x8,
                                                           (unsigned int*)w8);
        conv_stream_kernel<<<NTILES, 256, 0, stream>>>(x8, w8, bias, out);
    } else {
        conv_naive_kernel<<<(N_OUT + 255) / 256, 256, 0, stream>>>(x, wgt, bias, out);
    }
}

// Round 11
// 43.040 us; speedup vs baseline: 1.3661x; 1.3661x over previous
//
#include <hip/hip_runtime.h>

typedef int int4v __attribute__((ext_vector_type(4)));

// Problem constants
#define IN_C    64
#define OUT_C   128
#define KTOT    576
#define N_W     73728       // 128*3*3*64
#define N_OUT   25690112

// Fused-pair tiling: block = 16x8 output pixels (two 8x8 tiles stacked
// vertically), 18x10 halo in LDS. 64 images x 28 blocks = 1792 blocks
// (21 pair-blocks + 7 singleton bottom-row blocks per image).
#define PIXB    80          // bytes per halo pixel slot (64 data + 16 pad)
#define NBLKS   1792

// ---------------------------------------------------------------------------
// Pack weights into fragment order for mfma_i32_16x16x64_i8 (vectorized).
//   dest byte t = ((kt*8 + nt)*64 + lane)*16 + byte
//   holds W[k][n], k = kt*64 + (lane>>4)*16 + byte, n = nt*16 + (lane&15)
__global__ __launch_bounds__(256) void pack_w_kernel(const int* __restrict__ wgt,
                                                     unsigned int* __restrict__ w8) {
    int t = blockIdx.x * 256 + threadIdx.x;   // t < 18432
    int d = t << 2;
    int byte = d & 15;
    int lane = (d >> 4) & 63;
    int ntk  = d >> 10;
    int nt   = ntk & 7;
    int kt   = ntk >> 3;
    int k = kt * 64 + ((lane >> 4) << 4) + byte;
    int n = nt * 16 + (lane & 15);
    int4v v = *(const int4v*)(wgt + n * KTOT + k);
    w8[t] = (v.x & 0xff) | ((v.y & 0xff) << 8) | ((v.z & 0xff) << 16)
          | ((unsigned int)v.w << 24);
}

__device__ __forceinline__ int pack4(int4v a) {
    return (a.x & 0xff) | ((a.y & 0xff) << 8) | ((a.z & 0xff) << 16) | (a.w << 24);
}

// ---------------------------------------------------------------------------
// Fused-pair halo conv. Block = two vertically-adjacent 8x8 tiles x 128 ch,
// 4 waves. One 18x10 halo staged once; two compute passes share it.
// A = weights (M=channels), B = x pixels -> D row = channel -> dwordx4 stores.
__global__ __launch_bounds__(256, 4) void conv_pair_kernel(const int* __restrict__ x32,
                                                           const char* __restrict__ w8,
                                                           const int* __restrict__ bias,
                                                           int* __restrict__ out) {
    __shared__ char hx[180 * PIXB];           // 14400 B

    const int tid  = threadIdx.x;
    const int lane = tid & 63;
    const int wv   = tid >> 6;
    const int l15  = lane & 15;
    const int l4   = lane >> 4;

    // XCD-chunked bijective swizzle: 1792 = 8 XCDs x 224 (8 whole images).
    const int bid = blockIdx.x;
    const int nb  = (bid & 7) * 224 + (bid >> 3);

    const int n   = nb / 28;
    const int bp  = nb - n * 28;
    const bool two = bp < 21;
    const int th0 = two ? (bp / 7) * 2 : 6;   // top tile row index
    const int tw  = two ? (bp % 7) : (bp - 21);
    const int h0  = th0 * 8 - 1;              // halo origin
    const int w0  = tw * 8 - 1;

    // ---- Phase 1: issue halo loads. 180 px x 4 quarters = 720 units of
    // (64B int32 -> 16B int8). unit = tid, tid+256, tid+512 (tid<208).
    const int q = tid & 3;                    // same for all 3 units
    const int px0 = tid >> 2;
    const int hr0 = px0 / 10, hc0 = px0 - hr0 * 10;
    const int px1 = px0 + 64;
    const int hr1 = px1 / 10, hc1 = px1 - hr1 * 10;
    const int px2 = px0 + 128;                // valid only tid<208 (px2<180)
    const int hr2 = px2 / 10, hc2 = px2 - hr2 * 10;
    const bool has2 = tid < 208;

    int4v rA0, rA1, rA2, rA3, rB0, rB1, rB2, rB3, rC0, rC1, rC2, rC3;
    const int gh0 = h0 + hr0, gw0 = w0 + hc0;
    const bool ok0 = ((unsigned)gh0 < 56u) & ((unsigned)gw0 < 56u);
    if (ok0) {
        const int4v* s = (const int4v*)x32 + (((n * 56 + gh0) * 56 + gw0) << 4) + (q << 2);
        rA0 = s[0]; rA1 = s[1]; rA2 = s[2]; rA3 = s[3];
    }
    const int gh1 = h0 + hr1, gw1 = w0 + hc1;
    const bool ok1 = ((unsigned)gh1 < 56u) & ((unsigned)gw1 < 56u);
    if (ok1) {
        const int4v* s = (const int4v*)x32 + (((n * 56 + gh1) * 56 + gw1) << 4) + (q << 2);
        rB0 = s[0]; rB1 = s[1]; rB2 = s[2]; rB3 = s[3];
    }
    const int gh2 = h0 + hr2, gw2 = w0 + hc2;
    const bool ok2 = has2 & ((unsigned)gh2 < 56u) & ((unsigned)gw2 < 56u);
    if (ok2) {
        const int4v* s = (const int4v*)x32 + (((n * 56 + gh2) * 56 + gw2) << 4) + (q << 2);
        rC0 = s[0]; rC1 = s[1]; rC2 = s[2]; rC3 = s[3];
    }
    __builtin_amdgcn_sched_barrier(0);

    // ---- Phase 2: depth-4 weight preload while halo loads are in flight.
    const char* wbase = w8 + (((wv * 2) * 64 + lane) << 4);
    const char* wb = wbase;
    int4v bR[4][2];
#pragma unroll
    for (int i = 0; i < 4; ++i) {
        bR[i][0] = *(const int4v*)(wb);
        bR[i][1] = *(const int4v*)(wb + 1024);
        wb += 8192;
    }
    __builtin_amdgcn_sched_barrier(0);

    // ---- Phase 3: pack + LDS write.
    {
        int4v pk = {0, 0, 0, 0};
        if (ok0) { pk.x = pack4(rA0); pk.y = pack4(rA1); pk.z = pack4(rA2); pk.w = pack4(rA3); }
        *(int4v*)(hx + px0 * PIXB + (q << 4)) = pk;
    }
    {
        int4v pk = {0, 0, 0, 0};
        if (ok1) { pk.x = pack4(rB0); pk.y = pack4(rB1); pk.z = pack4(rB2); pk.w = pack4(rB3); }
        *(int4v*)(hx + px1 * PIXB + (q << 4)) = pk;
    }
    if (has2) {
        int4v pk = {0, 0, 0, 0};
        if (ok2) { pk.x = pack4(rC0); pk.y = pack4(rC1); pk.z = pack4(rC2); pk.w = pack4(rC3); }
        *(int4v*)(hx + px2 * PIXB + (q << 4)) = pk;
    }
    __syncthreads();

    // Per-lane constants (shared by both tile passes).
    const char* ap0 = hx + ((l15 >> 3) * 10 + (l15 & 7)) * PIXB + (l4 << 4);
    const int chb = wv * 32 + (l4 << 2);
    const int4v bv0 = *(const int4v*)(bias + chb);
    const int4v bv1 = *(const int4v*)(bias + chb + 16);
    const int pc = l15 & 7;
    const int prl = l15 >> 3;

    // ================= Tile pass 1 (halo rows 0-9) =================
    int4v acc[4][2];
#pragma unroll
    for (int mt = 0; mt < 4; ++mt) {
        acc[mt][0] = (int4v){0, 0, 0, 0};
        acc[mt][1] = (int4v){0, 0, 0, 0};
    }
    int toff = 0;
#pragma unroll
    for (int kt = 0; kt < 9; ++kt) {
        int4v c0 = bR[kt & 3][0];
        int4v c1 = bR[kt & 3][1];
        if (kt < 5) {
            bR[kt & 3][0] = *(const int4v*)(wb);
            bR[kt & 3][1] = *(const int4v*)(wb + 1024);
            wb += 8192;
        }
#pragma unroll
        for (int mt = 0; mt < 4; ++mt) {
            int4v a = *(const int4v*)(ap0 + toff + mt * 1600);
            acc[mt][0] = __builtin_amdgcn_mfma_i32_16x16x64_i8(c0, a, acc[mt][0], 0, 0, 0);
            acc[mt][1] = __builtin_amdgcn_mfma_i32_16x16x64_i8(c1, a, acc[mt][1], 0, 0, 0);
        }
        toff += 80;
        if ((kt == 2) | (kt == 5)) toff += 560;
    }

    // Tile-2 weight preload issues before tile-1 stores (hides under drain).
    if (two) {
        wb = wbase;
#pragma unroll
        for (int i = 0; i < 4; ++i) {
            bR[i][0] = *(const int4v*)(wb);
            bR[i][1] = *(const int4v*)(wb + 1024);
            wb += 8192;
        }
    }
    __builtin_amdgcn_sched_barrier(0);

    {
        int* ob = out + (((n * 56 + th0 * 8) * 56 + tw * 8) << 7);
#pragma unroll
        for (int mt = 0; mt < 4; ++mt) {
            int pr = (mt << 1) + prl;
            int* o = ob + ((pr * 56 + pc) << 7) + chb;
            *(int4v*)(o)      = acc[mt][0] + bv0;
            *(int4v*)(o + 16) = acc[mt][1] + bv1;
        }
    }

    // ================= Tile pass 2 (halo rows 8-17) =================
    if (two) {
        const char* ap1 = ap0 + 8 * 800;       // +8 halo rows
#pragma unroll
        for (int mt = 0; mt < 4; ++mt) {
            acc[mt][0] = (int4v){0, 0, 0, 0};
            acc[mt][1] = (int4v){0, 0, 0, 0};
        }
        toff = 0;
#pragma unroll
        for (int kt = 0; kt < 9; ++kt) {
            int4v c0 = bR[kt & 3][0];
            int4v c1 = bR[kt & 3][1];
            if (kt < 5) {
                bR[kt & 3][0] = *(const int4v*)(wb);
                bR[kt & 3][1] = *(const int4v*)(wb + 1024);
                wb += 8192;
            }
#pragma unroll
            for (int mt = 0; mt < 4; ++mt) {
                int4v a = *(const int4v*)(ap1 + toff + mt * 1600);
                acc[mt][0] = __builtin_amdgcn_mfma_i32_16x16x64_i8(c0, a, acc[mt][0], 0, 0, 0);
                acc[mt][1] = __builtin_amdgcn_mfma_i32_16x16x64_i8(c1, a, acc[mt][1], 0, 0, 0);
            }
            toff += 80;
            if ((kt == 2) | (kt == 5)) toff += 560;
        }

        int* ob = out + (((n * 56 + (th0 + 1) * 8) * 56 + tw * 8) << 7);
#pragma unroll
        for (int mt = 0; mt < 4; ++mt) {
            int pr = (mt << 1) + prl;
            int* o = ob + ((pr * 56 + pc) << 7) + chb;
            *(int4v*)(o)      = acc[mt][0] + bv0;
            *(int4v*)(o + 16) = acc[mt][1] + bv1;
        }
    }
}

// ---------------------------------------------------------------------------
// Fallback (only if workspace is too small): direct conv, 1 thread/output.
__global__ __launch_bounds__(256) void conv_naive_kernel(const int* __restrict__ x,
                                                         const int* __restrict__ wgt,
                                                         const int* __restrict__ bias,
                                                         int* __restrict__ out) {
    int idx = blockIdx.x * 256 + threadIdx.x;
    if (idx >= N_OUT) return;
    int ch  = idx & 127;
    int pix = idx >> 7;
    int n  = pix / 3136;
    int r2 = pix - n * 3136;
    int h  = r2 / 56;
    int w  = r2 - h * 56;
    int acc = bias[ch];
    for (int kh = 0; kh < 3; ++kh) {
        int hxr = h + kh - 1;
        if ((unsigned)hxr >= 56u) continue;
        for (int kw = 0; kw < 3; ++kw) {
            int wx = w + kw - 1;
            if ((unsigned)wx >= 56u) continue;
            const int* xp = x + ((n * 56 + hxr) * 56 + wx) * 64;
            const int* wp = wgt + ch * KTOT + (kh * 3 + kw) * 64;
            for (int ic = 0; ic < 64; ++ic) acc += xp[ic] * wp[ic];
        }
    }
    out[idx] = acc;
}

// ---------------------------------------------------------------------------
extern "C" void kernel_launch(void* const* d_in, const int* in_sizes, int n_in,
                              void* d_out, int out_size, void* d_ws, size_t ws_size,
                              hipStream_t stream) {
    const int* x    = (const int*)d_in[0];
    const int* wgt  = (const int*)d_in[1];
    const int* bias = (const int*)d_in[2];
    int* out = (int*)d_out;

    if (ws_size >= (size_t)(N_W + 8192)) {
        char* w8 = (char*)d_ws;              // N_W bytes + 8KB prefetch tail
        pack_w_kernel<<<N_W / 4 / 256, 256, 0, stream>>>(wgt, (unsigned int*)w8);
        conv_pair_kernel<<<NBLKS, 256, 0, stream>>>(x, w8, bias, out);
    } else {
        conv_naive_kernel<<<(N_OUT + 255) / 256, 256, 0, stream>>>(x, wgt, bias, out);
    }
}